// Round 17
// baseline (402.842 us; speedup 1.0000x reference)
//
#include <hip/hip_runtime.h>
#include <hip/hip_fp16.h>
#include <math.h>

#define N_NODES 100000
#define N_EDGES 1600000
#define IN_CH 128
#define HID 64
#define HEADS 2
#define NEG_SLOPE 0.2f

#define NB_SCAN ((N_NODES + 255) / 256)   // 391 scan blocks
#define SHARD 12500                       // node shard: 100000 / 8
#define CHUNK_E 32768                     // edges per histogram chunk
#define NCHUNK ((N_EDGES + CHUNK_E - 1) / CHUNK_E)   // 49
#define BLK_PER_CHUNK (CHUNK_E / 256)     // 128

static __device__ inline ushort f2h(float f) { return __half_as_ushort(__float2half(f)); }
static __device__ inline float h2f(ushort u) { return __half2float(__ushort_as_half(u)); }
static __device__ inline void h8f(uint4 u, float f[8]) {
    f[0] = h2f((ushort)(u.x & 0xffff)); f[1] = h2f((ushort)(u.x >> 16));
    f[2] = h2f((ushort)(u.y & 0xffff)); f[3] = h2f((ushort)(u.y >> 16));
    f[4] = h2f((ushort)(u.z & 0xffff)); f[5] = h2f((ushort)(u.z >> 16));
    f[6] = h2f((ushort)(u.w & 0xffff)); f[7] = h2f((ushort)(u.w >> 16));
}
static __device__ inline float2 up2(uint w) {
    __half2 h = *(__half2*)&w;
    return __half22float2(h);
}
static __device__ inline uint pack2(float a, float b) {
    return (uint)f2h(a) | ((uint)f2h(b) << 16);
}

__device__ inline float leaky(float a) { return (a >= 0.0f) ? a : NEG_SLOPE * a; }

// ---------------- CSR build: zero global atomics ----------------
// Block = (chunk of 32768 edges, node shard of 12500). LDS histogram; the LDS
// atomicAdd return value IS the edge's rank within (chunk,node). Per-chunk counts
// <= ~8 (Binomial(32768,1e-5)) -> u8. Global atomics: none (round-2 lesson:
// 1.6M returning L2 atomics = 81us floor regardless of sharding).
__global__ __launch_bounds__(256) void k_hist(const int* __restrict__ dst,
                                              unsigned char* __restrict__ rank8,
                                              unsigned char* __restrict__ ctab8) {
    __shared__ uint bins[SHARD];          // 50 KB
    int c = blockIdx.x >> 3, s = blockIdx.x & 7;
    int base = s * SHARD;
    for (int i = threadIdx.x; i < SHARD; i += 256) bins[i] = 0;
    __syncthreads();
    int e0 = c * CHUNK_E;
    int e1 = e0 + CHUNK_E; if (e1 > N_EDGES) e1 = N_EDGES;
    for (int e = e0 + threadIdx.x; e < e1; e += 256) {
        int local = dst[e] - base;
        if ((unsigned)local < SHARD) {
            uint old = atomicAdd(&bins[local], 1u);
            rank8[e] = (unsigned char)old;
        }
    }
    __syncthreads();
    unsigned char* cc = ctab8 + (size_t)c * N_NODES + base;
    for (int i = threadIdx.x; i < SHARD; i += 256) cc[i] = (unsigned char)bins[i];
}

// per-node: total in-count + chunk-prefix bases, IN PLACE (read count, write base
// to the same byte; each thread owns its column -> no hazard). Then block scan.
__global__ void k_scan_a(unsigned char* __restrict__ ctab8,
                         int* __restrict__ cntN,
                         int* __restrict__ incl, int* __restrict__ bsum) {
    __shared__ int sh[256];
    int tid = threadIdx.x;
    int g = blockIdx.x * 256 + tid;
    int v = 0;
    if (g < N_NODES) {
        int run = 0;
        size_t idx = (size_t)g;
        for (int c = 0; c < NCHUNK; ++c, idx += N_NODES) {
            int cnt = ctab8[idx];
            ctab8[idx] = (unsigned char)run;   // overwrite count with prefix base
            run += cnt;
        }
        v = run;
        cntN[g] = run;
    }
    sh[tid] = v;
    __syncthreads();
    for (int off = 1; off < 256; off <<= 1) {
        int t = (tid >= off) ? sh[tid - off] : 0;
        __syncthreads();
        sh[tid] += t;
        __syncthreads();
    }
    if (g < N_NODES) incl[g] = sh[tid];
    if (tid == 255) bsum[blockIdx.x] = sh[255];
}

__global__ void k_scan_b(const int* __restrict__ bsum, int* __restrict__ boff) {
    __shared__ int sh[512];
    int tid = threadIdx.x;
    int v = (tid < NB_SCAN) ? bsum[tid] : 0;
    sh[tid] = v;
    __syncthreads();
    for (int off = 1; off < 512; off <<= 1) {
        int t = (tid >= off) ? sh[tid - off] : 0;
        __syncthreads();
        sh[tid] += t;
        __syncthreads();
    }
    if (tid < NB_SCAN) boff[tid] = sh[tid] - v;   // exclusive
}

__global__ void k_scan_c(const int* __restrict__ cntN, const int* __restrict__ incl,
                         const int* __restrict__ boff, int* rowptr) {
    int g = blockIdx.x * 256 + threadIdx.x;
    if (g >= N_NODES) return;
    int excl = incl[g] - cntN[g] + boff[blockIdx.x];
    rowptr[g] = excl;
    if (g == N_NODES - 1) rowptr[N_NODES] = incl[g] + boff[blockIdx.x];
}

// deterministic scatter: pos = rowptr[d] + ctab8[chunk][d] + rank8[e].
// Grid XCD-pinned: chunk c is processed only by blocks with blockIdx&7 == c&7,
// so each chunk's 100KB ctab8 slice lives in ONE XCD's L2 instead of 8.
__global__ void k_scatter(const int* __restrict__ src, const int* __restrict__ dst,
                          const float* __restrict__ ew,
                          const unsigned char* __restrict__ rank8,
                          const unsigned char* __restrict__ ctab8,
                          const int* __restrict__ rowptr, int2* __restrict__ ep) {
    int b = blockIdx.x;
    int x = b & 7;
    int g = b >> 3;
    int j = g & (BLK_PER_CHUNK - 1);      // 128 blocks of 256 threads per chunk
    int c = (g >> 7) * 8 + x;             // c & 7 == blockIdx & 7
    if (c >= NCHUNK) return;
    int e = c * CHUNK_E + j * 256 + threadIdx.x;
    if (e >= N_EDGES) return;
    int d = dst[e];
    int pos = rowptr[d] + (int)ctab8[(size_t)c * N_NODES + d] + (int)rank8[e];
    ep[pos] = make_int2(src[e], __float_as_int(ew[e]));
}

// deg/dinv from CSR: coalesced-ish sequential reads, no atomics (round-0 proven).
__global__ void k_deg_dinv(const int* __restrict__ rowptr, const int2* __restrict__ ep,
                           float* __restrict__ dinv) {
    int n = blockIdx.x * 256 + threadIdx.x;
    if (n >= N_NODES) return;
    int r0 = rowptr[n], r1 = rowptr[n + 1];
    float deg = 1.0f;
    for (int i = r0; i < r1; ++i) deg += __int_as_float(ep[i].y);
    dinv[n] = rsqrtf(deg);
}

// ---------------- dense: register-tiled GEMMs, padded LDS ----------------

// h1 = x @ gcn_w   [N,128]@[128,64] -> fp16.  K staged in two 64-chunks.
__global__ __launch_bounds__(256) void k_gemm1(const float* __restrict__ x,
                                               const float* __restrict__ w,
                                               ushort4* __restrict__ h1h) {
    __shared__ float sxT[64][65];    // [k][r], +1 pad: transpose store <=2-way conflict
    __shared__ float sw[128][64];    // [k][c]
    int t = threadIdx.x;
    int tx = t & 15, ty = t >> 4;
    int row0 = blockIdx.x * 64;
    for (int i = t; i < 128 * 16; i += 256)
        ((float4*)sw)[i] = ((const float4*)w)[i];
    float acc[4][4] = {};
    for (int c = 0; c < 2; ++c) {
        __syncthreads();   // chunk reuse guard (also orders after w staging for c=0)
        for (int i = t; i < 64 * 16; i += 256) {
            int r = i >> 4, kq = i & 15;
            int row = row0 + r;
            float4 v = make_float4(0.f, 0.f, 0.f, 0.f);
            if (row < N_NODES) v = ((const float4*)x)[row * 32 + c * 16 + kq];
            int k = kq * 4;
            sxT[k][r] = v.x; sxT[k + 1][r] = v.y; sxT[k + 2][r] = v.z; sxT[k + 3][r] = v.w;
        }
        __syncthreads();
        #pragma unroll 8
        for (int k = 0; k < 64; ++k) {
            float a0 = sxT[k][ty * 4], a1 = sxT[k][ty * 4 + 1];
            float a2 = sxT[k][ty * 4 + 2], a3 = sxT[k][ty * 4 + 3];
            float4 bb = *(const float4*)&sw[c * 64 + k][tx * 4];
            acc[0][0] += a0 * bb.x; acc[0][1] += a0 * bb.y; acc[0][2] += a0 * bb.z; acc[0][3] += a0 * bb.w;
            acc[1][0] += a1 * bb.x; acc[1][1] += a1 * bb.y; acc[1][2] += a1 * bb.z; acc[1][3] += a1 * bb.w;
            acc[2][0] += a2 * bb.x; acc[2][1] += a2 * bb.y; acc[2][2] += a2 * bb.z; acc[2][3] += a2 * bb.w;
            acc[3][0] += a3 * bb.x; acc[3][1] += a3 * bb.y; acc[3][2] += a3 * bb.z; acc[3][3] += a3 * bb.w;
        }
    }
    #pragma unroll
    for (int i = 0; i < 4; ++i) {
        int row = row0 + ty * 4 + i;
        if (row < N_NODES) {
            ushort4 o;
            o.x = f2h(acc[i][0]); o.y = f2h(acc[i][1]); o.z = f2h(acc[i][2]); o.w = f2h(acc[i][3]);
            h1h[row * 16 + tx] = o;
        }
    }
}

// h2 = agg1(fp16) @ gat_w [N,64]@[64,128] -> fp16; grid = tiles x 2 column halves.
// half == head: fused attention scores ss/sd from fp32 acc in epilogue.
__global__ __launch_bounds__(256) void k_gemm2(const uint4* __restrict__ a16,
                                               const float* __restrict__ w,
                                               const float* __restrict__ att_src,
                                               const float* __restrict__ att_dst,
                                               ushort4* __restrict__ h2h,
                                               float* __restrict__ ss, float* __restrict__ sd) {
    __shared__ float sxT[64][65];    // [k][r] padded
    __shared__ float swh[64][64];    // [k][c] (column half)
    int t = threadIdx.x;
    int tx = t & 15, ty = t >> 4;
    int tile = blockIdx.x >> 1, half = blockIdx.x & 1;
    int row0 = tile * 64;
    for (int i = t; i < 64 * 16; i += 256) {
        int k = i >> 4, cq = i & 15;
        float4 v = ((const float4*)(w + k * 128 + half * 64))[cq];
        ((float4*)&swh[k][cq * 4])[0] = v;
    }
    for (int i = t; i < 64 * 8; i += 256) {   // a tile: 64 rows x 8 uint4 (8 halves each)
        int r = i >> 3, j = i & 7;
        int row = row0 + r;
        float f[8] = {};
        if (row < N_NODES) { uint4 u = a16[row * 8 + j]; h8f(u, f); }
        int k = j * 8;
        #pragma unroll
        for (int m = 0; m < 8; ++m) sxT[k + m][r] = f[m];
    }
    __syncthreads();
    float acc[4][4] = {};
    #pragma unroll 8
    for (int k = 0; k < 64; ++k) {
        float a0 = sxT[k][ty * 4], a1 = sxT[k][ty * 4 + 1];
        float a2 = sxT[k][ty * 4 + 2], a3 = sxT[k][ty * 4 + 3];
        float4 bb = *(const float4*)&swh[k][tx * 4];
        acc[0][0] += a0 * bb.x; acc[0][1] += a0 * bb.y; acc[0][2] += a0 * bb.z; acc[0][3] += a0 * bb.w;
        acc[1][0] += a1 * bb.x; acc[1][1] += a1 * bb.y; acc[1][2] += a1 * bb.z; acc[1][3] += a1 * bb.w;
        acc[2][0] += a2 * bb.x; acc[2][1] += a2 * bb.y; acc[2][2] += a2 * bb.z; acc[2][3] += a2 * bb.w;
        acc[3][0] += a3 * bb.x; acc[3][1] += a3 * bb.y; acc[3][2] += a3 * bb.z; acc[3][3] += a3 * bb.w;
    }
    float as0 = att_src[half * 64 + tx * 4],     as1 = att_src[half * 64 + tx * 4 + 1];
    float as2 = att_src[half * 64 + tx * 4 + 2], as3 = att_src[half * 64 + tx * 4 + 3];
    float ad0 = att_dst[half * 64 + tx * 4],     ad1 = att_dst[half * 64 + tx * 4 + 1];
    float ad2 = att_dst[half * 64 + tx * 4 + 2], ad3 = att_dst[half * 64 + tx * 4 + 3];
    #pragma unroll
    for (int i = 0; i < 4; ++i) {
        int row = row0 + ty * 4 + i;
        float ps = acc[i][0] * as0 + acc[i][1] * as1 + acc[i][2] * as2 + acc[i][3] * as3;
        float pd = acc[i][0] * ad0 + acc[i][1] * ad1 + acc[i][2] * ad2 + acc[i][3] * ad3;
        #pragma unroll
        for (int off = 1; off < 16; off <<= 1) {
            ps += __shfl_xor(ps, off, 64);
            pd += __shfl_xor(pd, off, 64);
        }
        if (row < N_NODES) {
            if (tx == 0) { ss[row * 2 + half] = ps; sd[row * 2 + half] = pd; }
            ushort4 o;
            o.x = f2h(acc[i][0]); o.y = f2h(acc[i][1]); o.z = f2h(acc[i][2]); o.w = f2h(acc[i][3]);
            h2h[row * 32 + half * 16 + tx] = o;
        }
    }
}

// ---------------- segment gather kernels ----------------

// GCN: wave = node; lanes = 8 edge-groups x 8 (8 fp16 ch via uint4).
// 4-edge manual unroll: round-13 proved the latency theory (2-edge: 77.6->71.9us,
// VALUBusy 53->64%); 4 chains in flight deepens MLP further.
__global__ void k_gcn_csr(const int* __restrict__ rowptr, const int2* __restrict__ ep,
                          const float* __restrict__ dinv,
                          const uint4* __restrict__ h1q, const float* __restrict__ b,
                          uint4* __restrict__ agg1h) {
    int t = threadIdx.x;
    int n = blockIdx.x * 4 + (t >> 6);
    if (n >= N_NODES) return;
    int lane = t & 63, q = lane >> 3, r = lane & 7;
    int r0 = rowptr[n], r1 = rowptr[n + 1];
    float dn = dinv[n];
    float2 acc[4] = {};
    if (q == 0) {
        uint4 u = h1q[n * 8 + r];
        float2 d2 = make_float2(dn, dn);
        acc[0] = d2 * up2(u.x); acc[1] = d2 * up2(u.y);
        acc[2] = d2 * up2(u.z); acc[3] = d2 * up2(u.w);
    }
    int i = r0 + q;
    for (; i + 24 < r1; i += 32) {         // quad: edges i, i+8, i+16, i+24
        int2 ea = ep[i];
        int2 eb = ep[i + 8];
        int2 ec = ep[i + 16];
        int2 ed = ep[i + 24];
        float da = dinv[ea.x], db = dinv[eb.x], dc = dinv[ec.x], dd = dinv[ed.x];
        uint4 ua = h1q[ea.x * 8 + r];
        uint4 ub = h1q[eb.x * 8 + r];
        uint4 uc = h1q[ec.x * 8 + r];
        uint4 ud = h1q[ed.x * 8 + r];
        float wa = da * __int_as_float(ea.y), wb = db * __int_as_float(eb.y);
        float wc = dc * __int_as_float(ec.y), wd = dd * __int_as_float(ed.y);
        float2 w2a = make_float2(wa, wa), w2b = make_float2(wb, wb);
        float2 w2c = make_float2(wc, wc), w2d = make_float2(wd, wd);
        acc[0] += (w2a * up2(ua.x) + w2b * up2(ub.x)) + (w2c * up2(uc.x) + w2d * up2(ud.x));
        acc[1] += (w2a * up2(ua.y) + w2b * up2(ub.y)) + (w2c * up2(uc.y) + w2d * up2(ud.y));
        acc[2] += (w2a * up2(ua.z) + w2b * up2(ub.z)) + (w2c * up2(uc.z) + w2d * up2(ud.z));
        acc[3] += (w2a * up2(ua.w) + w2b * up2(ub.w)) + (w2c * up2(uc.w) + w2d * up2(ud.w));
    }
    for (; i < r1; i += 8) {               // tail singles (<=3)
        int2 e = ep[i];
        float wl = dinv[e.x] * __int_as_float(e.y);
        uint4 u = h1q[e.x * 8 + r];
        float2 w2 = make_float2(wl, wl);
        acc[0] += w2 * up2(u.x); acc[1] += w2 * up2(u.y);
        acc[2] += w2 * up2(u.z); acc[3] += w2 * up2(u.w);
    }
    float* av = (float*)acc;
    #pragma unroll
    for (int off = 8; off < 64; off <<= 1) {
        #pragma unroll
        for (int j = 0; j < 8; ++j) av[j] += __shfl_xor(av[j], off, 64);
    }
    if (q == 0) {
        float4 b0 = ((const float4*)b)[2 * r], b1 = ((const float4*)b)[2 * r + 1];
        float v0 = fmaxf(av[0] * dn + b0.x, 0.f), v1 = fmaxf(av[1] * dn + b0.y, 0.f);
        float v2 = fmaxf(av[2] * dn + b0.z, 0.f), v3 = fmaxf(av[3] * dn + b0.w, 0.f);
        float v4 = fmaxf(av[4] * dn + b1.x, 0.f), v5 = fmaxf(av[5] * dn + b1.y, 0.f);
        float v6 = fmaxf(av[6] * dn + b1.z, 0.f), v7 = fmaxf(av[7] * dn + b1.w, 0.f);
        uint4 o;
        o.x = pack2(v0, v1); o.y = pack2(v2, v3); o.z = pack2(v4, v5); o.w = pack2(v6, v7);
        agg1h[n * 8 + r] = o;
    }
}

// GAT: ONE wave = one node, BOTH heads. 4 edge-groups x 16 lanes.
// 4-edge manual unroll (round-13: 2-edge gave +8%, VALUBusy 64% -> still ~36%
// stall; mean deg 16 / 4 groups = 4 edges/group, so one quad iter covers the
// typical node). Issue all 4 ep loads, then 4 ss, then 4 rows before consuming.
__global__ void k_gat_csr(const int* __restrict__ rowptr, const int2* __restrict__ ep,
                          const float* __restrict__ ss, const float* __restrict__ sd,
                          const uint4* __restrict__ h2q, const float* __restrict__ b,
                          float* __restrict__ out) {
    int t = threadIdx.x;
    int n = blockIdx.x * 4 + (t >> 6);
    if (n >= N_NODES) return;
    int lane = t & 63;
    int g = lane >> 4;            // edge group 0..3
    int t16 = lane & 15;          // uint4 slot in the 256B row
    int head = t16 >> 3;          // 0: ch 0..63 of head0, 1: head1
    int r = t16 & 7;              // channel-octet index within head
    int r0 = rowptr[n], r1 = rowptr[n + 1];
    float sdn = sd[n * 2 + head];
    float den = 0.f;
    float2 acc[4] = {};
    if (g == 0) {                 // self-loop term (counted once per head via butterfly)
        float exs = __expf(leaky(ss[n * 2 + head] + sdn));
        den = exs;
        uint4 u = h2q[n * 16 + t16];
        float2 e2 = make_float2(exs, exs);
        acc[0] = e2 * up2(u.x); acc[1] = e2 * up2(u.y);
        acc[2] = e2 * up2(u.z); acc[3] = e2 * up2(u.w);
    }
    int i = r0 + g;
    for (; i + 12 < r1; i += 16) {  // quad: edges i, i+4, i+8, i+12
        int s0 = ep[i].x;
        int s1 = ep[i + 4].x;
        int s2 = ep[i + 8].x;
        int s3 = ep[i + 12].x;
        float sa0 = ss[s0 * 2 + head];
        float sa1 = ss[s1 * 2 + head];
        float sa2 = ss[s2 * 2 + head];
        float sa3 = ss[s3 * 2 + head];
        uint4 u0 = h2q[s0 * 16 + t16];
        uint4 u1 = h2q[s1 * 16 + t16];
        uint4 u2 = h2q[s2 * 16 + t16];
        uint4 u3 = h2q[s3 * 16 + t16];
        float ex0 = __expf(leaky(sa0 + sdn));
        float ex1 = __expf(leaky(sa1 + sdn));
        float ex2 = __expf(leaky(sa2 + sdn));
        float ex3 = __expf(leaky(sa3 + sdn));
        den += (ex0 + ex1) + (ex2 + ex3);
        float2 e0 = make_float2(ex0, ex0), e1 = make_float2(ex1, ex1);
        float2 e2 = make_float2(ex2, ex2), e3 = make_float2(ex3, ex3);
        acc[0] += (e0 * up2(u0.x) + e1 * up2(u1.x)) + (e2 * up2(u2.x) + e3 * up2(u3.x));
        acc[1] += (e0 * up2(u0.y) + e1 * up2(u1.y)) + (e2 * up2(u2.y) + e3 * up2(u3.y));
        acc[2] += (e0 * up2(u0.z) + e1 * up2(u1.z)) + (e2 * up2(u2.z) + e3 * up2(u3.z));
        acc[3] += (e0 * up2(u0.w) + e1 * up2(u1.w)) + (e2 * up2(u2.w) + e3 * up2(u3.w));
    }
    for (; i < r1; i += 4) {      // tail singles (<=3)
        int s = ep[i].x;
        float ex = __expf(leaky(ss[s * 2 + head] + sdn));
        den += ex;
        uint4 u = h2q[s * 16 + t16];
        float2 e2 = make_float2(ex, ex);
        acc[0] += e2 * up2(u.x); acc[1] += e2 * up2(u.y);
        acc[2] += e2 * up2(u.z); acc[3] += e2 * up2(u.w);
    }
    // reduce across the 4 edge-groups (preserves head: offsets 16,32 keep lane&15)
    float* av = (float*)acc;
    #pragma unroll
    for (int off = 16; off < 64; off <<= 1) {
        #pragma unroll
        for (int j = 0; j < 8; ++j) av[j] += __shfl_xor(av[j], off, 64);
        den += __shfl_xor(den, off, 64);
    }
    float inv = 1.0f / fmaxf(den, 1e-16f);
    #pragma unroll
    for (int j = 0; j < 8; ++j) av[j] *= inv;
    // mean over heads: partner lane differs only in bit 3
    float o[8];
    #pragma unroll
    for (int j = 0; j < 8; ++j) o[j] = 0.5f * (av[j] + __shfl_xor(av[j], 8, 64));
    if (g == 0 && head == 0) {    // 8 lanes x 8 channels = 64 outputs
        float4 b0 = ((const float4*)b)[2 * r], b1 = ((const float4*)b)[2 * r + 1];
        float4* op = (float4*)(out + n * 64 + r * 8);
        op[0] = make_float4(fmaxf(o[0] + b0.x, 0.f), fmaxf(o[1] + b0.y, 0.f),
                            fmaxf(o[2] + b0.z, 0.f), fmaxf(o[3] + b0.w, 0.f));
        op[1] = make_float4(fmaxf(o[4] + b1.x, 0.f), fmaxf(o[5] + b1.y, 0.f),
                            fmaxf(o[6] + b1.z, 0.f), fmaxf(o[7] + b1.w, 0.f));
    }
}

// ---------------- launch ----------------
extern "C" void kernel_launch(void* const* d_in, const int* in_sizes, int n_in,
                              void* d_out, int out_size, void* d_ws, size_t ws_size,
                              hipStream_t stream) {
    const float* x       = (const float*)d_in[0];
    const int*   eidx    = (const int*)d_in[1];
    const float* ew      = (const float*)d_in[2];
    const float* gcn_w   = (const float*)d_in[3];
    const float* gcn_b   = (const float*)d_in[4];
    const float* gat_w   = (const float*)d_in[5];
    const float* att_src = (const float*)d_in[6];
    const float* att_dst = (const float*)d_in[7];
    const float* gat_b   = (const float*)d_in[8];
    float* out = (float*)d_out;

    const int* src = eidx;            // edge_index[0]
    const int* dst = eidx + N_EDGES;  // edge_index[1]

    // workspace layout (16B-aligned blocks first, byte arrays last) ~74 MB total
    char* p = (char*)d_ws;
    ushort* agg1h = (ushort*)p; p += sizeof(ushort) * (size_t)N_NODES * 64;   // fp16
    ushort* h1h   = (ushort*)p; p += sizeof(ushort) * (size_t)N_NODES * 64;   // fp16
    ushort* h2h   = (ushort*)p; p += sizeof(ushort) * (size_t)N_NODES * 128;  // fp16
    int2*  ep     = (int2*)p;   p += sizeof(int2) * (size_t)N_EDGES;          // {src, raw ew}
    float* dinv   = (float*)p;  p += sizeof(float) * N_NODES;
    int*   incl   = (int*)p;    p += sizeof(int) * N_NODES;
    int*   cntN   = (int*)p;    p += sizeof(int) * N_NODES;
    int*   rowptr = (int*)p;    p += sizeof(int) * (N_NODES + 1);
    float* ss     = (float*)p;  p += sizeof(float) * N_NODES * 2;
    float* sd     = (float*)p;  p += sizeof(float) * N_NODES * 2;
    int*   bsum   = (int*)p;    p += sizeof(int) * NB_SCAN;
    int*   boff   = (int*)p;    p += sizeof(int) * NB_SCAN;
    unsigned char* ctab8 = (unsigned char*)p; p += (size_t)NCHUNK * N_NODES;  // 4.9 MB (count->base in place)
    unsigned char* rank8 = (unsigned char*)p; p += (size_t)N_EDGES;           // 1.6 MB

    const int T = 256;

    // CSR build: LDS-histogram ranks (no global atomics, no memset needed)
    k_hist<<<NCHUNK * 8, T, 0, stream>>>(dst, rank8, ctab8);
    k_scan_a<<<NB_SCAN, T, 0, stream>>>(ctab8, cntN, incl, bsum);
    k_scan_b<<<1, 512, 0, stream>>>(bsum, boff);
    k_scan_c<<<NB_SCAN, T, 0, stream>>>(cntN, incl, boff, rowptr);
    k_scatter<<<((NCHUNK + 7) / 8) * BLK_PER_CHUNK * 8, T, 0, stream>>>(src, dst, ew, rank8, ctab8, rowptr, ep);
    k_deg_dinv<<<NB_SCAN, T, 0, stream>>>(rowptr, ep, dinv);

    // layer 1: GCN
    k_gemm1<<<(N_NODES + 63) / 64, T, 0, stream>>>(x, gcn_w, (ushort4*)h1h);
    k_gcn_csr<<<(N_NODES + 3) / 4, T, 0, stream>>>(rowptr, ep, dinv, (const uint4*)h1h, gcn_b, (uint4*)agg1h);

    // layer 2: GAT (scores fused into gemm2 epilogue)
    k_gemm2<<<((N_NODES + 63) / 64) * 2, T, 0, stream>>>((const uint4*)agg1h, gat_w, att_src, att_dst, (ushort4*)h2h, ss, sd);
    k_gat_csr<<<(N_NODES + 3) / 4, T, 0, stream>>>(rowptr, ep, ss, sd, (const uint4*)h2h, gat_b, out);
}

// Round 18
// 377.064 us; speedup vs baseline: 1.0684x; 1.0684x over previous
//
#include <hip/hip_runtime.h>
#include <hip/hip_fp16.h>
#include <math.h>

#define N_NODES 100000
#define N_EDGES 1600000
#define IN_CH 128
#define HID 64
#define HEADS 2
#define NEG_SLOPE 0.2f

#define NB_SCAN ((N_NODES + 255) / 256)   // 391 scan blocks
#define SHARD 12500                       // node shard: 100000 / 8
#define CHUNK_E 32768                     // edges per histogram chunk
#define NCHUNK ((N_EDGES + CHUNK_E - 1) / CHUNK_E)   // 49
#define BLK_PER_CHUNK (CHUNK_E / 256)     // 128

static __device__ inline ushort f2h(float f) { return __half_as_ushort(__float2half(f)); }
static __device__ inline float h2f(ushort u) { return __half2float(__ushort_as_half(u)); }
static __device__ inline void h8f(uint4 u, float f[8]) {
    f[0] = h2f((ushort)(u.x & 0xffff)); f[1] = h2f((ushort)(u.x >> 16));
    f[2] = h2f((ushort)(u.y & 0xffff)); f[3] = h2f((ushort)(u.y >> 16));
    f[4] = h2f((ushort)(u.z & 0xffff)); f[5] = h2f((ushort)(u.z >> 16));
    f[6] = h2f((ushort)(u.w & 0xffff)); f[7] = h2f((ushort)(u.w >> 16));
}
// packed f16x2 -> f32x2 (compiler emits v_cvt_f32_f16 + op_sel either way; kept for clarity)
static __device__ inline float2 up2(uint w) {
    __half2 h = *(__half2*)&w;
    return __half22float2(h);
}
static __device__ inline uint pack2(float a, float b) {
    return (uint)f2h(a) | ((uint)f2h(b) << 16);
}

__device__ inline float leaky(float a) { return (a >= 0.0f) ? a : NEG_SLOPE * a; }

// ---------------- CSR build: zero global atomics ----------------
// Block = (chunk of 32768 edges, node shard of 12500). LDS histogram; the LDS
// atomicAdd return value IS the edge's rank within (chunk,node). Per-chunk counts
// <= ~8 (Binomial(32768,1e-5)) -> u8. Global atomics: none (round-2 lesson:
// 1.6M returning L2 atomics = 81us floor regardless of sharding).
__global__ __launch_bounds__(256) void k_hist(const int* __restrict__ dst,
                                              unsigned char* __restrict__ rank8,
                                              unsigned char* __restrict__ ctab8) {
    __shared__ uint bins[SHARD];          // 50 KB
    int c = blockIdx.x >> 3, s = blockIdx.x & 7;
    int base = s * SHARD;
    for (int i = threadIdx.x; i < SHARD; i += 256) bins[i] = 0;
    __syncthreads();
    int e0 = c * CHUNK_E;
    int e1 = e0 + CHUNK_E; if (e1 > N_EDGES) e1 = N_EDGES;
    for (int e = e0 + threadIdx.x; e < e1; e += 256) {
        int local = dst[e] - base;
        if ((unsigned)local < SHARD) {
            uint old = atomicAdd(&bins[local], 1u);
            rank8[e] = (unsigned char)old;
        }
    }
    __syncthreads();
    unsigned char* cc = ctab8 + (size_t)c * N_NODES + base;
    for (int i = threadIdx.x; i < SHARD; i += 256) cc[i] = (unsigned char)bins[i];
}

// per-node: total in-count + chunk-prefix bases, IN PLACE (read count, write base
// to the same byte; each thread owns its column -> no hazard). Then block scan.
__global__ void k_scan_a(unsigned char* __restrict__ ctab8,
                         int* __restrict__ cntN,
                         int* __restrict__ incl, int* __restrict__ bsum) {
    __shared__ int sh[256];
    int tid = threadIdx.x;
    int g = blockIdx.x * 256 + tid;
    int v = 0;
    if (g < N_NODES) {
        int run = 0;
        size_t idx = (size_t)g;
        for (int c = 0; c < NCHUNK; ++c, idx += N_NODES) {
            int cnt = ctab8[idx];
            ctab8[idx] = (unsigned char)run;   // overwrite count with prefix base
            run += cnt;
        }
        v = run;
        cntN[g] = run;
    }
    sh[tid] = v;
    __syncthreads();
    for (int off = 1; off < 256; off <<= 1) {
        int t = (tid >= off) ? sh[tid - off] : 0;
        __syncthreads();
        sh[tid] += t;
        __syncthreads();
    }
    if (g < N_NODES) incl[g] = sh[tid];
    if (tid == 255) bsum[blockIdx.x] = sh[255];
}

__global__ void k_scan_b(const int* __restrict__ bsum, int* __restrict__ boff) {
    __shared__ int sh[512];
    int tid = threadIdx.x;
    int v = (tid < NB_SCAN) ? bsum[tid] : 0;
    sh[tid] = v;
    __syncthreads();
    for (int off = 1; off < 512; off <<= 1) {
        int t = (tid >= off) ? sh[tid - off] : 0;
        __syncthreads();
        sh[tid] += t;
        __syncthreads();
    }
    if (tid < NB_SCAN) boff[tid] = sh[tid] - v;   // exclusive
}

__global__ void k_scan_c(const int* __restrict__ cntN, const int* __restrict__ incl,
                         const int* __restrict__ boff, int* rowptr) {
    int g = blockIdx.x * 256 + threadIdx.x;
    if (g >= N_NODES) return;
    int excl = incl[g] - cntN[g] + boff[blockIdx.x];
    rowptr[g] = excl;
    if (g == N_NODES - 1) rowptr[N_NODES] = incl[g] + boff[blockIdx.x];
}

// deterministic scatter: pos = rowptr[d] + ctab8[chunk][d] + rank8[e].
// Grid XCD-pinned: chunk c is processed only by blocks with blockIdx&7 == c&7,
// so each chunk's 100KB ctab8 slice lives in ONE XCD's L2 instead of 8.
__global__ void k_scatter(const int* __restrict__ src, const int* __restrict__ dst,
                          const float* __restrict__ ew,
                          const unsigned char* __restrict__ rank8,
                          const unsigned char* __restrict__ ctab8,
                          const int* __restrict__ rowptr, int2* __restrict__ ep) {
    int b = blockIdx.x;
    int x = b & 7;
    int g = b >> 3;
    int j = g & (BLK_PER_CHUNK - 1);      // 128 blocks of 256 threads per chunk
    int c = (g >> 7) * 8 + x;             // c & 7 == blockIdx & 7
    if (c >= NCHUNK) return;
    int e = c * CHUNK_E + j * 256 + threadIdx.x;
    if (e >= N_EDGES) return;
    int d = dst[e];
    int pos = rowptr[d] + (int)ctab8[(size_t)c * N_NODES + d] + (int)rank8[e];
    ep[pos] = make_int2(src[e], __float_as_int(ew[e]));
}

// deg/dinv from CSR: coalesced-ish sequential reads, no atomics (round-0 proven).
__global__ void k_deg_dinv(const int* __restrict__ rowptr, const int2* __restrict__ ep,
                           float* __restrict__ dinv) {
    int n = blockIdx.x * 256 + threadIdx.x;
    if (n >= N_NODES) return;
    int r0 = rowptr[n], r1 = rowptr[n + 1];
    float deg = 1.0f;
    for (int i = r0; i < r1; ++i) deg += __int_as_float(ep[i].y);
    dinv[n] = rsqrtf(deg);
}

// ---------------- dense: register-tiled GEMMs, padded LDS ----------------

// h1 = x @ gcn_w   [N,128]@[128,64] -> fp16.  K staged in two 64-chunks.
__global__ __launch_bounds__(256) void k_gemm1(const float* __restrict__ x,
                                               const float* __restrict__ w,
                                               ushort4* __restrict__ h1h) {
    __shared__ float sxT[64][65];    // [k][r], +1 pad: transpose store <=2-way conflict
    __shared__ float sw[128][64];    // [k][c]
    int t = threadIdx.x;
    int tx = t & 15, ty = t >> 4;
    int row0 = blockIdx.x * 64;
    for (int i = t; i < 128 * 16; i += 256)
        ((float4*)sw)[i] = ((const float4*)w)[i];
    float acc[4][4] = {};
    for (int c = 0; c < 2; ++c) {
        __syncthreads();   // chunk reuse guard (also orders after w staging for c=0)
        for (int i = t; i < 64 * 16; i += 256) {
            int r = i >> 4, kq = i & 15;
            int row = row0 + r;
            float4 v = make_float4(0.f, 0.f, 0.f, 0.f);
            if (row < N_NODES) v = ((const float4*)x)[row * 32 + c * 16 + kq];
            int k = kq * 4;
            sxT[k][r] = v.x; sxT[k + 1][r] = v.y; sxT[k + 2][r] = v.z; sxT[k + 3][r] = v.w;
        }
        __syncthreads();
        #pragma unroll 8
        for (int k = 0; k < 64; ++k) {
            float a0 = sxT[k][ty * 4], a1 = sxT[k][ty * 4 + 1];
            float a2 = sxT[k][ty * 4 + 2], a3 = sxT[k][ty * 4 + 3];
            float4 bb = *(const float4*)&sw[c * 64 + k][tx * 4];
            acc[0][0] += a0 * bb.x; acc[0][1] += a0 * bb.y; acc[0][2] += a0 * bb.z; acc[0][3] += a0 * bb.w;
            acc[1][0] += a1 * bb.x; acc[1][1] += a1 * bb.y; acc[1][2] += a1 * bb.z; acc[1][3] += a1 * bb.w;
            acc[2][0] += a2 * bb.x; acc[2][1] += a2 * bb.y; acc[2][2] += a2 * bb.z; acc[2][3] += a2 * bb.w;
            acc[3][0] += a3 * bb.x; acc[3][1] += a3 * bb.y; acc[3][2] += a3 * bb.z; acc[3][3] += a3 * bb.w;
        }
    }
    #pragma unroll
    for (int i = 0; i < 4; ++i) {
        int row = row0 + ty * 4 + i;
        if (row < N_NODES) {
            ushort4 o;
            o.x = f2h(acc[i][0]); o.y = f2h(acc[i][1]); o.z = f2h(acc[i][2]); o.w = f2h(acc[i][3]);
            h1h[row * 16 + tx] = o;
        }
    }
}

// h2 = agg1(fp16) @ gat_w [N,64]@[64,128] -> fp16; grid = tiles x 2 column halves.
// half == head: fused attention scores ss/sd from fp32 acc in epilogue.
__global__ __launch_bounds__(256) void k_gemm2(const uint4* __restrict__ a16,
                                               const float* __restrict__ w,
                                               const float* __restrict__ att_src,
                                               const float* __restrict__ att_dst,
                                               ushort4* __restrict__ h2h,
                                               float* __restrict__ ss, float* __restrict__ sd) {
    __shared__ float sxT[64][65];    // [k][r] padded
    __shared__ float swh[64][64];    // [k][c] (column half)
    int t = threadIdx.x;
    int tx = t & 15, ty = t >> 4;
    int tile = blockIdx.x >> 1, half = blockIdx.x & 1;
    int row0 = tile * 64;
    for (int i = t; i < 64 * 16; i += 256) {
        int k = i >> 4, cq = i & 15;
        float4 v = ((const float4*)(w + k * 128 + half * 64))[cq];
        ((float4*)&swh[k][cq * 4])[0] = v;
    }
    for (int i = t; i < 64 * 8; i += 256) {   // a tile: 64 rows x 8 uint4 (8 halves each)
        int r = i >> 3, j = i & 7;
        int row = row0 + r;
        float f[8] = {};
        if (row < N_NODES) { uint4 u = a16[row * 8 + j]; h8f(u, f); }
        int k = j * 8;
        #pragma unroll
        for (int m = 0; m < 8; ++m) sxT[k + m][r] = f[m];
    }
    __syncthreads();
    float acc[4][4] = {};
    #pragma unroll 8
    for (int k = 0; k < 64; ++k) {
        float a0 = sxT[k][ty * 4], a1 = sxT[k][ty * 4 + 1];
        float a2 = sxT[k][ty * 4 + 2], a3 = sxT[k][ty * 4 + 3];
        float4 bb = *(const float4*)&swh[k][tx * 4];
        acc[0][0] += a0 * bb.x; acc[0][1] += a0 * bb.y; acc[0][2] += a0 * bb.z; acc[0][3] += a0 * bb.w;
        acc[1][0] += a1 * bb.x; acc[1][1] += a1 * bb.y; acc[1][2] += a1 * bb.z; acc[1][3] += a1 * bb.w;
        acc[2][0] += a2 * bb.x; acc[2][1] += a2 * bb.y; acc[2][2] += a2 * bb.z; acc[2][3] += a2 * bb.w;
        acc[3][0] += a3 * bb.x; acc[3][1] += a3 * bb.y; acc[3][2] += a3 * bb.z; acc[3][3] += a3 * bb.w;
    }
    float as0 = att_src[half * 64 + tx * 4],     as1 = att_src[half * 64 + tx * 4 + 1];
    float as2 = att_src[half * 64 + tx * 4 + 2], as3 = att_src[half * 64 + tx * 4 + 3];
    float ad0 = att_dst[half * 64 + tx * 4],     ad1 = att_dst[half * 64 + tx * 4 + 1];
    float ad2 = att_dst[half * 64 + tx * 4 + 2], ad3 = att_dst[half * 64 + tx * 4 + 3];
    #pragma unroll
    for (int i = 0; i < 4; ++i) {
        int row = row0 + ty * 4 + i;
        float ps = acc[i][0] * as0 + acc[i][1] * as1 + acc[i][2] * as2 + acc[i][3] * as3;
        float pd = acc[i][0] * ad0 + acc[i][1] * ad1 + acc[i][2] * ad2 + acc[i][3] * ad3;
        #pragma unroll
        for (int off = 1; off < 16; off <<= 1) {
            ps += __shfl_xor(ps, off, 64);
            pd += __shfl_xor(pd, off, 64);
        }
        if (row < N_NODES) {
            if (tx == 0) { ss[row * 2 + half] = ps; sd[row * 2 + half] = pd; }
            ushort4 o;
            o.x = f2h(acc[i][0]); o.y = f2h(acc[i][1]); o.z = f2h(acc[i][2]); o.w = f2h(acc[i][3]);
            h2h[row * 32 + half * 16 + tx] = o;
        }
    }
}

// ---------------- segment gather kernels ----------------

// GCN: wave = node; lanes = 8 edge-groups x 8 (8 fp16 ch via uint4).
// 2-edge manual unroll: round-13-verified optimum. Round-17 showed 4-edge is
// neutral-to-negative (VGPR 32, occupancy down, dur +1.2us) -> 2 chains already
// saturate the L2-miss/fabric path for random 256B gathers.
__global__ void k_gcn_csr(const int* __restrict__ rowptr, const int2* __restrict__ ep,
                          const float* __restrict__ dinv,
                          const uint4* __restrict__ h1q, const float* __restrict__ b,
                          uint4* __restrict__ agg1h) {
    int t = threadIdx.x;
    int n = blockIdx.x * 4 + (t >> 6);
    if (n >= N_NODES) return;
    int lane = t & 63, q = lane >> 3, r = lane & 7;
    int r0 = rowptr[n], r1 = rowptr[n + 1];
    float dn = dinv[n];
    float2 acc[4] = {};
    if (q == 0) {
        uint4 u = h1q[n * 8 + r];
        float2 d2 = make_float2(dn, dn);
        acc[0] = d2 * up2(u.x); acc[1] = d2 * up2(u.y);
        acc[2] = d2 * up2(u.z); acc[3] = d2 * up2(u.w);
    }
    int i = r0 + q;
    for (; i + 8 < r1; i += 16) {          // pair: edges i and i+8 (independent chains)
        int2 ea = ep[i];
        int2 eb = ep[i + 8];
        float da = dinv[ea.x];
        float db = dinv[eb.x];
        uint4 ua = h1q[ea.x * 8 + r];
        uint4 ub = h1q[eb.x * 8 + r];
        float wa = da * __int_as_float(ea.y);
        float wb = db * __int_as_float(eb.y);
        float2 w2a = make_float2(wa, wa), w2b = make_float2(wb, wb);
        acc[0] += w2a * up2(ua.x) + w2b * up2(ub.x);
        acc[1] += w2a * up2(ua.y) + w2b * up2(ub.y);
        acc[2] += w2a * up2(ua.z) + w2b * up2(ub.z);
        acc[3] += w2a * up2(ua.w) + w2b * up2(ub.w);
    }
    if (i < r1) {                          // tail single
        int2 e = ep[i];
        float wl = dinv[e.x] * __int_as_float(e.y);
        uint4 u = h1q[e.x * 8 + r];
        float2 w2 = make_float2(wl, wl);
        acc[0] += w2 * up2(u.x); acc[1] += w2 * up2(u.y);
        acc[2] += w2 * up2(u.z); acc[3] += w2 * up2(u.w);
    }
    float* av = (float*)acc;
    #pragma unroll
    for (int off = 8; off < 64; off <<= 1) {
        #pragma unroll
        for (int j = 0; j < 8; ++j) av[j] += __shfl_xor(av[j], off, 64);
    }
    if (q == 0) {
        float4 b0 = ((const float4*)b)[2 * r], b1 = ((const float4*)b)[2 * r + 1];
        float v0 = fmaxf(av[0] * dn + b0.x, 0.f), v1 = fmaxf(av[1] * dn + b0.y, 0.f);
        float v2 = fmaxf(av[2] * dn + b0.z, 0.f), v3 = fmaxf(av[3] * dn + b0.w, 0.f);
        float v4 = fmaxf(av[4] * dn + b1.x, 0.f), v5 = fmaxf(av[5] * dn + b1.y, 0.f);
        float v6 = fmaxf(av[6] * dn + b1.z, 0.f), v7 = fmaxf(av[7] * dn + b1.w, 0.f);
        uint4 o;
        o.x = pack2(v0, v1); o.y = pack2(v2, v3); o.z = pack2(v4, v5); o.w = pack2(v6, v7);
        agg1h[n * 8 + r] = o;
    }
}

// GAT: ONE wave = one node, BOTH heads. 4 edge-groups x 16 lanes.
// 2-edge manual unroll (round-13-verified optimum; round-17 proved 4-edge
// neutral-to-negative): issue both ep loads, both ss loads, both h2q row loads
// before consuming -> 2 independent chains in flight per group.
__global__ void k_gat_csr(const int* __restrict__ rowptr, const int2* __restrict__ ep,
                          const float* __restrict__ ss, const float* __restrict__ sd,
                          const uint4* __restrict__ h2q, const float* __restrict__ b,
                          float* __restrict__ out) {
    int t = threadIdx.x;
    int n = blockIdx.x * 4 + (t >> 6);
    if (n >= N_NODES) return;
    int lane = t & 63;
    int g = lane >> 4;            // edge group 0..3
    int t16 = lane & 15;          // uint4 slot in the 256B row
    int head = t16 >> 3;          // 0: ch 0..63 of head0, 1: head1
    int r = t16 & 7;              // channel-octet index within head
    int r0 = rowptr[n], r1 = rowptr[n + 1];
    float sdn = sd[n * 2 + head];
    float den = 0.f;
    float2 acc[4] = {};
    if (g == 0) {                 // self-loop term (counted once per head via butterfly)
        float exs = __expf(leaky(ss[n * 2 + head] + sdn));
        den = exs;
        uint4 u = h2q[n * 16 + t16];
        float2 e2 = make_float2(exs, exs);
        acc[0] = e2 * up2(u.x); acc[1] = e2 * up2(u.y);
        acc[2] = e2 * up2(u.z); acc[3] = e2 * up2(u.w);
    }
    int i = r0 + g;
    for (; i + 4 < r1; i += 8) {  // pair: edges i and i+4 (independent chains)
        int s0 = ep[i].x;
        int s1 = ep[i + 4].x;
        float sa0 = ss[s0 * 2 + head];
        float sa1 = ss[s1 * 2 + head];
        uint4 u0 = h2q[s0 * 16 + t16];
        uint4 u1 = h2q[s1 * 16 + t16];
        float ex0 = __expf(leaky(sa0 + sdn));
        float ex1 = __expf(leaky(sa1 + sdn));
        den += ex0 + ex1;
        float2 e0 = make_float2(ex0, ex0), e1 = make_float2(ex1, ex1);
        acc[0] += e0 * up2(u0.x) + e1 * up2(u1.x);
        acc[1] += e0 * up2(u0.y) + e1 * up2(u1.y);
        acc[2] += e0 * up2(u0.z) + e1 * up2(u1.z);
        acc[3] += e0 * up2(u0.w) + e1 * up2(u1.w);
    }
    if (i < r1) {                 // tail single
        int s = ep[i].x;
        float ex = __expf(leaky(ss[s * 2 + head] + sdn));
        den += ex;
        uint4 u = h2q[s * 16 + t16];
        float2 e2 = make_float2(ex, ex);
        acc[0] += e2 * up2(u.x); acc[1] += e2 * up2(u.y);
        acc[2] += e2 * up2(u.z); acc[3] += e2 * up2(u.w);
    }
    // reduce across the 4 edge-groups (preserves head: offsets 16,32 keep lane&15)
    float* av = (float*)acc;
    #pragma unroll
    for (int off = 16; off < 64; off <<= 1) {
        #pragma unroll
        for (int j = 0; j < 8; ++j) av[j] += __shfl_xor(av[j], off, 64);
        den += __shfl_xor(den, off, 64);
    }
    float inv = 1.0f / fmaxf(den, 1e-16f);
    #pragma unroll
    for (int j = 0; j < 8; ++j) av[j] *= inv;
    // mean over heads: partner lane differs only in bit 3
    float o[8];
    #pragma unroll
    for (int j = 0; j < 8; ++j) o[j] = 0.5f * (av[j] + __shfl_xor(av[j], 8, 64));
    if (g == 0 && head == 0) {    // 8 lanes x 8 channels = 64 outputs
        float4 b0 = ((const float4*)b)[2 * r], b1 = ((const float4*)b)[2 * r + 1];
        float4* op = (float4*)(out + n * 64 + r * 8);
        op[0] = make_float4(fmaxf(o[0] + b0.x, 0.f), fmaxf(o[1] + b0.y, 0.f),
                            fmaxf(o[2] + b0.z, 0.f), fmaxf(o[3] + b0.w, 0.f));
        op[1] = make_float4(fmaxf(o[4] + b1.x, 0.f), fmaxf(o[5] + b1.y, 0.f),
                            fmaxf(o[6] + b1.z, 0.f), fmaxf(o[7] + b1.w, 0.f));
    }
}

// ---------------- launch ----------------
extern "C" void kernel_launch(void* const* d_in, const int* in_sizes, int n_in,
                              void* d_out, int out_size, void* d_ws, size_t ws_size,
                              hipStream_t stream) {
    const float* x       = (const float*)d_in[0];
    const int*   eidx    = (const int*)d_in[1];
    const float* ew      = (const float*)d_in[2];
    const float* gcn_w   = (const float*)d_in[3];
    const float* gcn_b   = (const float*)d_in[4];
    const float* gat_w   = (const float*)d_in[5];
    const float* att_src = (const float*)d_in[6];
    const float* att_dst = (const float*)d_in[7];
    const float* gat_b   = (const float*)d_in[8];
    float* out = (float*)d_out;

    const int* src = eidx;            // edge_index[0]
    const int* dst = eidx + N_EDGES;  // edge_index[1]

    // workspace layout (16B-aligned blocks first, byte arrays last) ~74 MB total
    char* p = (char*)d_ws;
    ushort* agg1h = (ushort*)p; p += sizeof(ushort) * (size_t)N_NODES * 64;   // fp16
    ushort* h1h   = (ushort*)p; p += sizeof(ushort) * (size_t)N_NODES * 64;   // fp16
    ushort* h2h   = (ushort*)p; p += sizeof(ushort) * (size_t)N_NODES * 128;  // fp16
    int2*  ep     = (int2*)p;   p += sizeof(int2) * (size_t)N_EDGES;          // {src, raw ew}
    float* dinv   = (float*)p;  p += sizeof(float) * N_NODES;
    int*   incl   = (int*)p;    p += sizeof(int) * N_NODES;
    int*   cntN   = (int*)p;    p += sizeof(int) * N_NODES;
    int*   rowptr = (int*)p;    p += sizeof(int) * (N_NODES + 1);
    float* ss     = (float*)p;  p += sizeof(float) * N_NODES * 2;
    float* sd     = (float*)p;  p += sizeof(float) * N_NODES * 2;
    int*   bsum   = (int*)p;    p += sizeof(int) * NB_SCAN;
    int*   boff   = (int*)p;    p += sizeof(int) * NB_SCAN;
    unsigned char* ctab8 = (unsigned char*)p; p += (size_t)NCHUNK * N_NODES;  // 4.9 MB (count->base in place)
    unsigned char* rank8 = (unsigned char*)p; p += (size_t)N_EDGES;           // 1.6 MB

    const int T = 256;

    // CSR build: LDS-histogram ranks (no global atomics, no memset needed)
    k_hist<<<NCHUNK * 8, T, 0, stream>>>(dst, rank8, ctab8);
    k_scan_a<<<NB_SCAN, T, 0, stream>>>(ctab8, cntN, incl, bsum);
    k_scan_b<<<1, 512, 0, stream>>>(bsum, boff);
    k_scan_c<<<NB_SCAN, T, 0, stream>>>(cntN, incl, boff, rowptr);
    k_scatter<<<((NCHUNK + 7) / 8) * BLK_PER_CHUNK * 8, T, 0, stream>>>(src, dst, ew, rank8, ctab8, rowptr, ep);
    k_deg_dinv<<<NB_SCAN, T, 0, stream>>>(rowptr, ep, dinv);

    // layer 1: GCN
    k_gemm1<<<(N_NODES + 63) / 64, T, 0, stream>>>(x, gcn_w, (ushort4*)h1h);
    k_gcn_csr<<<(N_NODES + 3) / 4, T, 0, stream>>>(rowptr, ep, dinv, (const uint4*)h1h, gcn_b, (uint4*)agg1h);

    // layer 2: GAT (scores fused into gemm2 epilogue)
    k_gemm2<<<((N_NODES + 63) / 64) * 2, T, 0, stream>>>((const uint4*)agg1h, gat_w, att_src, att_dst, (ushort4*)h2h, ss, sd);
    k_gat_csr<<<(N_NODES + 3) / 4, T, 0, stream>>>(rowptr, ep, ss, sd, (const uint4*)h2h, gat_b, out);
}